// Round 8
// baseline (92.468 us; speedup 1.0000x reference)
//
#include <hip/hip_runtime.h>
#include <hip/hip_bf16.h>
#include <math.h>

#define HALF_LOG_2PI 0.9189385332046727f
#define WIN 32.0f
#define TILE_T 16
#define KPAD 96      // max window tokens per 16-frame tile is <= 81 (spacing>=1)
#define MROWPAD 104  // ushort row stride for sMT: 208 B = 16*13 -> b128-aligned
#define WROWPAD 108  // float row stride for w_s: 432 B = 16*27 -> b128-aligned

typedef float f32x4 __attribute__((ext_vector_type(4)));
typedef short bf16x8 __attribute__((ext_vector_type(8)));

// ---------------------------------------------------------------------------
// Kernel 1: mask-mode detect + per-row cumsum (center) + amp/inv_sigma.
// One block per batch row, blockDim = Tin.  (round-3 verbatim)
// ---------------------------------------------------------------------------
__global__ void prep_k(const float* __restrict__ duration,
                       const float* __restrict__ sigma,
                       const void* __restrict__ mask,
                       float* __restrict__ center,
                       float* __restrict__ amp,
                       float* __restrict__ inv_sigma,
                       int B, int Tin) {
    __shared__ float s[1024];
    __shared__ int s_not[2];
    int b = blockIdx.x, i = threadIdx.x;
    if (i < 2) s_not[i] = 0;
    __syncthreads();
    {   // detect over first B*Tin/4 words (minimum size over all modes)
        const unsigned int* mw = (const unsigned int*)mask;
        int nwords = (B * Tin) >> 2;
        int nI = 0, nF = 0;
        for (int k = i; k < nwords; k += blockDim.x) {
            unsigned int w = mw[k];
            nI |= (w != 0u && w != 1u);
            nF |= (w != 0u && w != 0x3F800000u);
        }
        if (nI) atomicOr(&s_not[0], 1);
        if (nF) atomicOr(&s_not[1], 1);
    }
    size_t gi = (size_t)b * Tin + i;
    float d = duration[gi];
    s[i] = d;
    __syncthreads();
    for (int off = 1; off < Tin; off <<= 1) {
        float v = (i >= off) ? s[i - off] : 0.0f;
        __syncthreads();
        s[i] += v;
        __syncthreads();
    }
    float c = s[i] - 0.5f * d;
    int mode = s_not[0] ? (s_not[1] ? 2 : 1) : 0;
    bool m;
    if (mode == 0)      m = ((const int*)mask)[gi] != 0;
    else if (mode == 1) m = ((const float*)mask)[gi] != 0.0f;
    else                m = ((const unsigned char*)mask)[gi] != 0;
    float sg = sigma[gi];
    center[gi]    = c;
    inv_sigma[gi] = 1.0f / sg;
    amp[gi]       = m ? 0.0f : __expf(-__logf(sg) - HALF_LOG_2PI);
}

// ---------------------------------------------------------------------------
// Kernel 2: inv_den / lo / cnt per (b,t).  (round-3 verbatim)
// ---------------------------------------------------------------------------
__global__ __launch_bounds__(256) void denom_k(
        const float* __restrict__ center, const float* __restrict__ amp,
        const float* __restrict__ inv_sigma,
        float* __restrict__ inv_den, int* __restrict__ lo_out,
        int* __restrict__ cnt_out, int Tin, int Tout) {
    __shared__ float sc[1024], sa[1024], si[1024];
    int b = blockIdx.y;
    int t = blockIdx.x * 256 + threadIdx.x;
    for (int i = threadIdx.x; i < Tin; i += 256) {
        size_t g = (size_t)b * Tin + i;
        sc[i] = center[g]; sa[i] = amp[g]; si[i] = inv_sigma[g];
    }
    __syncthreads();
    if (t >= Tout) return;
    float tf = (float)t;
    int lo = 0, hi = Tin;
    while (lo < hi) {                 // first i with center >= t - WIN
        int mid = (lo + hi) >> 1;
        if (sc[mid] < tf - WIN) lo = mid + 1; else hi = mid;
    }
    float sum = 0.0f;
    int i = lo;
    for (; i < Tin; ++i) {
        float cc = sc[i];
        if (cc > tf + WIN) break;
        float z = (tf - cc) * si[i];
        sum += sa[i] * __expf(-0.5f * z * z);
    }
    size_t g = (size_t)b * Tout + t;
    inv_den[g]  = 1.0f / (sum + 1e-8f);
    lo_out[g]   = lo;
    cnt_out[g]  = i - lo;
}

// ---------------------------------------------------------------------------
// Kernel 3: attn rows, one block per (b,i).  (round-3 verbatim)
// ---------------------------------------------------------------------------
__global__ __launch_bounds__(256) void attn_k(
        const float* __restrict__ center, const float* __restrict__ amp,
        const float* __restrict__ inv_sigma, const float* __restrict__ inv_den,
        float* __restrict__ attn, int Tin, int Tout) {
    int bi = blockIdx.x;
    int b  = bi / Tin;
    float c = center[bi], a = amp[bi], inv = inv_sigma[bi];
    const float* iden = inv_den + (size_t)b * Tout;
    float* row = attn + (size_t)bi * Tout;
    for (int t4 = threadIdx.x * 4; t4 < Tout; t4 += 256 * 4) {
        f32x4 rv;
        if ((float)(t4 + 3) < c - WIN || (float)t4 > c + WIN) {
            rv = (f32x4)0.0f;
        } else {
            #pragma unroll
            for (int j = 0; j < 4; ++j) {
                float dlt = (float)(t4 + j) - c;
                if (fabsf(dlt) < WIN) {
                    float z = dlt * inv;
                    rv[j] = a * __expf(-0.5f * z * z) * iden[t4 + j];
                } else rv[j] = 0.0f;
            }
        }
        __builtin_nontemporal_store(rv, (f32x4*)(row + t4));
    }
}

// ---------------------------------------------------------------------------
// Kernel 4 (NEW): upsample tile via bf16 MFMA.
// out[t0..t0+15][0..255] = W (16 x K) @ M (K x 256), K = wcnt <= 81, pad 96.
//   - w_s[16][108] fp32: normalized weights (x inv_den), zero-padded.
//   - sMT[256][104] bf16: memory tile TRANSPOSED (sMT[n][k] = mem[lo0+k][n])
//     so the B-fragment (lane n=l&15 needs column n across k) is a single
//     aligned ds_read_b128 per k-step.
//   - A-frag: lane m=l&15 reads w_s[m][k0..k0+7] (f32x4 x2) and cvt_pk's to
//     bf16x8 in-register.  C/D: n=l&15, m=(l>>4)*4+reg (m89-verified).
//   - 4 waves x 4 n-chunks x 3 k-steps = 48 MFMA per block.
// ---------------------------------------------------------------------------
__global__ __launch_bounds__(256) void upsample_k(
        const float* __restrict__ mem, const float* __restrict__ center,
        const float* __restrict__ amp, const float* __restrict__ inv_sigma,
        const float* __restrict__ inv_den, const int* __restrict__ lo_ws,
        const int* __restrict__ cnt_ws, float* __restrict__ out,
        int Tin, int Tout, int D) {
    __shared__ __align__(16) float w_s[TILE_T][WROWPAD];
    __shared__ __align__(16) unsigned short sMT[256][MROWPAD];
    __shared__ float s_iden[TILE_T];
    __shared__ int s_lo, s_cnt;
    int nwg = gridDim.x;
    int wid = blockIdx.x;
    int work = wid;
    if ((nwg & 7) == 0) {                 // XCD-chunked swizzle (8 XCDs)
        int chunk = nwg >> 3;
        work = (wid & 7) * chunk + (wid >> 3);
    }
    int tpb = Tout / TILE_T;
    int b   = work / tpb;
    int t0  = (work - b * tpb) * TILE_T;
    int tid = threadIdx.x;
    if (tid == 0) {
        size_t g0 = (size_t)b * Tout + t0;
        size_t g1 = g0 + (TILE_T - 1);
        int lo0 = lo_ws[g0];
        int cnt = lo_ws[g1] + cnt_ws[g1] - lo0;
        s_lo  = lo0;
        s_cnt = cnt > KPAD ? KPAD : cnt;  // mathematically <= 81
    }
    if (tid < TILE_T) s_iden[tid] = inv_den[(size_t)b * Tout + t0 + tid];
    __syncthreads();
    int lo0 = s_lo, wcnt = s_cnt;

    // ---- fill normalized weights (zero-padded to KPAD) ----
    for (int id = tid; id < TILE_T * KPAD; id += 256) {
        int f = id / KPAD, w = id - f * KPAD;
        float wgt = 0.0f;
        if (w < wcnt) {                   // lo0+w < Tin guaranteed by cnt
            size_t gi = (size_t)b * Tin + lo0 + w;
            float dlt = (float)(t0 + f) - center[gi];
            if (fabsf(dlt) < WIN) {
                float z = dlt * inv_sigma[gi];
                wgt = amp[gi] * __expf(-0.5f * z * z) * s_iden[f];
            }
        }
        w_s[f][w] = wgt;
    }
    // ---- stage memory tile transposed, fp32 -> bf16 (RNE pairs) ----
    {
        const float* mcol = mem + ((size_t)b * Tin + lo0) * D + tid;
        #pragma unroll 4
        for (int r = 0; r < KPAD; r += 2) {
            float m0 = (r     < wcnt) ? mcol[(size_t)r * D]       : 0.0f;
            float m1 = (r + 1 < wcnt) ? mcol[(size_t)(r + 1) * D] : 0.0f;
            __hip_bfloat162 h2 = __float22bfloat162_rn(make_float2(m0, m1));
            *(unsigned*)&sMT[tid][r] = *(unsigned*)&h2;
        }
    }
    __syncthreads();

    int lane = tid & 63, wave = tid >> 6;
    int m16 = lane & 15, kg = lane >> 4;
    // ---- A-fragments: 3 k-steps, cvt in-register ----
    bf16x8 afr[3];
    #pragma unroll
    for (int s = 0; s < 3; ++s) {
        int k0 = s * 32 + kg * 8;
        f32x4 a0 = *(const f32x4*)&w_s[m16][k0];
        f32x4 a1 = *(const f32x4*)&w_s[m16][k0 + 4];
        __hip_bfloat162 p0 = __float22bfloat162_rn(make_float2(a0.x, a0.y));
        __hip_bfloat162 p1 = __float22bfloat162_rn(make_float2(a0.z, a0.w));
        __hip_bfloat162 p2 = __float22bfloat162_rn(make_float2(a1.x, a1.y));
        __hip_bfloat162 p3 = __float22bfloat162_rn(make_float2(a1.z, a1.w));
        union { bf16x8 v; unsigned u[4]; } au;
        au.u[0] = *(unsigned*)&p0; au.u[1] = *(unsigned*)&p1;
        au.u[2] = *(unsigned*)&p2; au.u[3] = *(unsigned*)&p3;
        afr[s] = au.v;
    }
    // ---- MFMA + epilogue: wave owns n in [wave*64, wave*64+64) ----
    #pragma unroll
    for (int q = 0; q < 4; ++q) {
        int nb = wave * 64 + q * 16;
        f32x4 acc = {0.0f, 0.0f, 0.0f, 0.0f};
        #pragma unroll
        for (int s = 0; s < 3; ++s) {
            int k0 = s * 32 + kg * 8;
            bf16x8 bfr = *(const bf16x8*)&sMT[nb + m16][k0];
            acc = __builtin_amdgcn_mfma_f32_16x16x32_bf16(afr[s], bfr, acc,
                                                          0, 0, 0);
        }
        int n = nb + m16;
        #pragma unroll
        for (int r = 0; r < 4; ++r) {
            int m = kg * 4 + r;
            __builtin_nontemporal_store(
                acc[r], out + ((size_t)(b * Tout + t0 + m)) * D + n);
        }
    }
}

extern "C" void kernel_launch(void* const* d_in, const int* in_sizes, int n_in,
                              void* d_out, int out_size, void* d_ws, size_t ws_size,
                              hipStream_t stream) {
    const float* memory   = (const float*)d_in[0];
    const float* duration = (const float*)d_in[1];
    const float* sigma    = (const float*)d_in[2];
    const void*  mask     = d_in[4];          // d_in[3]=output_lengths (unused)

    int B    = in_sizes[3];
    int Tin  = in_sizes[1] / B;
    int D    = in_sizes[0] / (B * Tin);
    int Tout = out_size / (B * (D + Tin));

    float* out_up   = (float*)d_out;
    float* out_attn = out_up + (size_t)B * Tout * D;

    // workspace layout
    float* center = (float*)d_ws;
    float* amp    = center + (size_t)B * Tin;
    float* inv    = amp    + (size_t)B * Tin;
    float* iden   = inv    + (size_t)B * Tin;
    int*   lo     = (int*)(iden + (size_t)B * Tout);
    int*   cnt    = lo + (size_t)B * Tout;

    prep_k<<<B, Tin, 0, stream>>>(duration, sigma, mask,
                                  center, amp, inv, B, Tin);
    denom_k<<<dim3((Tout + 255) / 256, B), 256, 0, stream>>>(
        center, amp, inv, iden, lo, cnt, Tin, Tout);
    attn_k<<<B * Tin, 256, 0, stream>>>(center, amp, inv, iden,
                                        out_attn, Tin, Tout);
    upsample_k<<<(B * Tout) / TILE_T, 256, 0, stream>>>(
        memory, center, amp, inv, iden, lo, cnt, out_up, Tin, Tout, D);
}

// Round 9
// 78.639 us; speedup vs baseline: 1.1759x; 1.1759x over previous
//
#include <hip/hip_runtime.h>
#include <hip/hip_bf16.h>
#include <math.h>

#define HALF_LOG_2PI 0.9189385332046727f
#define WIN 32.0f
#define TILE_T 16
#define KPAD 96      // max window tokens per 16-frame tile <= 81 (spacing>=1)
#define NLOC 64      // n-columns per upsample block
#define MRP 104      // ushorts per sMT row: 208 B, 16B-aligned for b128
#define WRP 100      // floats per w_s row: 400 B, 16B-aligned

typedef float f32x4 __attribute__((ext_vector_type(4)));
typedef short bf16x8 __attribute__((ext_vector_type(8)));

// ---------------------------------------------------------------------------
// Kernel 1: mask-mode detect + per-row cumsum (center) + amp/inv_sigma.
// One block per batch row, blockDim = Tin.  (round-3 verbatim)
// ---------------------------------------------------------------------------
__global__ void prep_k(const float* __restrict__ duration,
                       const float* __restrict__ sigma,
                       const void* __restrict__ mask,
                       float* __restrict__ center,
                       float* __restrict__ amp,
                       float* __restrict__ inv_sigma,
                       int B, int Tin) {
    __shared__ float s[1024];
    __shared__ int s_not[2];
    int b = blockIdx.x, i = threadIdx.x;
    if (i < 2) s_not[i] = 0;
    __syncthreads();
    {   // detect over first B*Tin/4 words (minimum size over all modes)
        const unsigned int* mw = (const unsigned int*)mask;
        int nwords = (B * Tin) >> 2;
        int nI = 0, nF = 0;
        for (int k = i; k < nwords; k += blockDim.x) {
            unsigned int w = mw[k];
            nI |= (w != 0u && w != 1u);
            nF |= (w != 0u && w != 0x3F800000u);
        }
        if (nI) atomicOr(&s_not[0], 1);
        if (nF) atomicOr(&s_not[1], 1);
    }
    size_t gi = (size_t)b * Tin + i;
    float d = duration[gi];
    s[i] = d;
    __syncthreads();
    for (int off = 1; off < Tin; off <<= 1) {
        float v = (i >= off) ? s[i - off] : 0.0f;
        __syncthreads();
        s[i] += v;
        __syncthreads();
    }
    float c = s[i] - 0.5f * d;
    int mode = s_not[0] ? (s_not[1] ? 2 : 1) : 0;
    bool m;
    if (mode == 0)      m = ((const int*)mask)[gi] != 0;
    else if (mode == 1) m = ((const float*)mask)[gi] != 0.0f;
    else                m = ((const unsigned char*)mask)[gi] != 0;
    float sg = sigma[gi];
    center[gi]    = c;
    inv_sigma[gi] = 1.0f / sg;
    amp[gi]       = m ? 0.0f : __expf(-__logf(sg) - HALF_LOG_2PI);
}

// ---------------------------------------------------------------------------
// Kernel 2: inv_den / lo / cnt per (b,t).  (round-3 verbatim)
// ---------------------------------------------------------------------------
__global__ __launch_bounds__(256) void denom_k(
        const float* __restrict__ center, const float* __restrict__ amp,
        const float* __restrict__ inv_sigma,
        float* __restrict__ inv_den, int* __restrict__ lo_out,
        int* __restrict__ cnt_out, int Tin, int Tout) {
    __shared__ float sc[1024], sa[1024], si[1024];
    int b = blockIdx.y;
    int t = blockIdx.x * 256 + threadIdx.x;
    for (int i = threadIdx.x; i < Tin; i += 256) {
        size_t g = (size_t)b * Tin + i;
        sc[i] = center[g]; sa[i] = amp[g]; si[i] = inv_sigma[g];
    }
    __syncthreads();
    if (t >= Tout) return;
    float tf = (float)t;
    int lo = 0, hi = Tin;
    while (lo < hi) {                 // first i with center >= t - WIN
        int mid = (lo + hi) >> 1;
        if (sc[mid] < tf - WIN) lo = mid + 1; else hi = mid;
    }
    float sum = 0.0f;
    int i = lo;
    for (; i < Tin; ++i) {
        float cc = sc[i];
        if (cc > tf + WIN) break;
        float z = (tf - cc) * si[i];
        sum += sa[i] * __expf(-0.5f * z * z);
    }
    size_t g = (size_t)b * Tout + t;
    inv_den[g]  = 1.0f / (sum + 1e-8f);
    lo_out[g]   = lo;
    cnt_out[g]  = i - lo;
}

// ---------------------------------------------------------------------------
// Kernel 3: attn rows, one block per (b,i).  (round-3 verbatim)
// ---------------------------------------------------------------------------
__global__ __launch_bounds__(256) void attn_k(
        const float* __restrict__ center, const float* __restrict__ amp,
        const float* __restrict__ inv_sigma, const float* __restrict__ inv_den,
        float* __restrict__ attn, int Tin, int Tout) {
    int bi = blockIdx.x;
    int b  = bi / Tin;
    float c = center[bi], a = amp[bi], inv = inv_sigma[bi];
    const float* iden = inv_den + (size_t)b * Tout;
    float* row = attn + (size_t)bi * Tout;
    for (int t4 = threadIdx.x * 4; t4 < Tout; t4 += 256 * 4) {
        f32x4 rv;
        if ((float)(t4 + 3) < c - WIN || (float)t4 > c + WIN) {
            rv = (f32x4)0.0f;
        } else {
            #pragma unroll
            for (int j = 0; j < 4; ++j) {
                float dlt = (float)(t4 + j) - c;
                if (fabsf(dlt) < WIN) {
                    float z = dlt * inv;
                    rv[j] = a * __expf(-0.5f * z * z) * iden[t4 + j];
                } else rv[j] = 0.0f;
            }
        }
        __builtin_nontemporal_store(rv, (f32x4*)(row + t4));
    }
}

// ---------------------------------------------------------------------------
// Kernel 4: upsample via bf16 MFMA, occupancy-first geometry.
// Block = (b, 16-frame tile t0, 64-col chunk n0): out[t0..15][n0..63] =
// W(16 x K) @ M(K x 64), K = wcnt <= 81 (pad KPAD=96).
//   - w_s[16][100] fp32 normalized weights (zero-padded).
//   - sMT[64][104] bf16: M chunk transposed (sMT[n][k] = mem[lo0+k][n0+n]);
//     staged as paired-bf16 b32 writes (wave w owns k-pairs it*4+w).
//   - ~20 KB LDS -> 8 blocks/CU (32 waves): staging latency hidden (the R7
//     failure was 60 KB -> 2 blocks/CU).
//   - per wave: 3 MFMAs (one 16x16 output, K-accumulated), lane mappings
//     hardware-verified by R7's passing run.
// ---------------------------------------------------------------------------
__global__ __launch_bounds__(256) void upsample_k(
        const float* __restrict__ mem, const float* __restrict__ center,
        const float* __restrict__ amp, const float* __restrict__ inv_sigma,
        const float* __restrict__ inv_den, const int* __restrict__ lo_ws,
        const int* __restrict__ cnt_ws, float* __restrict__ out,
        int Tin, int Tout, int D) {
    __shared__ __align__(16) float w_s[TILE_T][WRP];
    __shared__ __align__(16) unsigned short sMT[NLOC][MRP];
    __shared__ float s_iden[TILE_T];
    __shared__ int s_lo, s_cnt;
    int nwg = gridDim.x;
    int wid = blockIdx.x;
    int work = wid;
    if ((nwg & 7) == 0) {                 // XCD-chunked swizzle (8 XCDs)
        int chunk = nwg >> 3;
        work = (wid & 7) * chunk + (wid >> 3);
    }
    int tpb4 = (Tout / TILE_T) * 4;       // (t0,n0) tiles per batch
    int b    = work / tpb4;
    int rem  = work - b * tpb4;
    int t0   = (rem >> 2) * TILE_T;
    int n0   = (rem & 3) * NLOC;
    int tid  = threadIdx.x;
    if (tid == 0) {
        size_t g0 = (size_t)b * Tout + t0;
        size_t g1 = g0 + (TILE_T - 1);
        int lo0 = lo_ws[g0];
        int cnt = lo_ws[g1] + cnt_ws[g1] - lo0;
        s_lo  = lo0;
        s_cnt = cnt > KPAD ? KPAD : cnt;  // mathematically <= 81
    }
    if (tid < TILE_T) s_iden[tid] = inv_den[(size_t)b * Tout + t0 + tid];
    __syncthreads();
    int lo0 = s_lo, wcnt = s_cnt;

    // ---- normalized weights, zero-padded to KPAD (6 slots/thread) ----
    for (int id = tid; id < TILE_T * KPAD; id += 256) {
        int f = id / KPAD, w = id - f * KPAD;
        float wgt = 0.0f;
        if (w < wcnt) {
            size_t gi = (size_t)b * Tin + lo0 + w;
            float dlt = (float)(t0 + f) - center[gi];
            if (fabsf(dlt) < WIN) {
                float z = dlt * inv_sigma[gi];
                wgt = amp[gi] * __expf(-0.5f * z * z) * s_iden[f];
            }
        }
        w_s[f][w] = wgt;
    }
    // ---- stage M^T chunk: wave wv handles k-pair (it*4+wv), lanes = n ----
    {
        int wv = tid >> 6, n = tid & 63;
        const float* mbase = mem + ((size_t)b * Tin + lo0) * D + n0 + n;
        #pragma unroll
        for (int it = 0; it < (KPAD / 2) / 4; ++it) {   // 12 iters
            int k = (it * 4 + wv) * 2;
            float m0 = (k     < wcnt) ? mbase[(size_t)k * D]       : 0.0f;
            float m1 = (k + 1 < wcnt) ? mbase[(size_t)(k + 1) * D] : 0.0f;
            __hip_bfloat162 h2 = __float22bfloat162_rn(make_float2(m0, m1));
            *(unsigned*)&sMT[n][k] = *(unsigned*)&h2;
        }
    }
    __syncthreads();

    int lane = tid & 63, wv = tid >> 6;
    int m16 = lane & 15, kg = lane >> 4;
    f32x4 acc = {0.0f, 0.0f, 0.0f, 0.0f};
    #pragma unroll
    for (int s = 0; s < 3; ++s) {
        int k0 = s * 32 + kg * 8;
        // A-frag: lane m=m16 holds W[m16][k0..k0+7], cvt'd in-register
        f32x4 a0 = *(const f32x4*)&w_s[m16][k0];
        f32x4 a1 = *(const f32x4*)&w_s[m16][k0 + 4];
        __hip_bfloat162 p0 = __float22bfloat162_rn(make_float2(a0.x, a0.y));
        __hip_bfloat162 p1 = __float22bfloat162_rn(make_float2(a0.z, a0.w));
        __hip_bfloat162 p2 = __float22bfloat162_rn(make_float2(a1.x, a1.y));
        __hip_bfloat162 p3 = __float22bfloat162_rn(make_float2(a1.z, a1.w));
        union { bf16x8 v; unsigned u[4]; } au;
        au.u[0] = *(unsigned*)&p0; au.u[1] = *(unsigned*)&p1;
        au.u[2] = *(unsigned*)&p2; au.u[3] = *(unsigned*)&p3;
        // B-frag: lane n=m16 reads sMT[wave_n + m16][k0..k0+7] (b128)
        bf16x8 bfr = *(const bf16x8*)&sMT[wv * 16 + m16][k0];
        acc = __builtin_amdgcn_mfma_f32_16x16x32_bf16(au.v, bfr, acc, 0, 0, 0);
    }
    // C/D: col = n0 + wv*16 + m16, row = kg*4 + r  (R7-verified mapping)
    int n = n0 + wv * 16 + m16;
    #pragma unroll
    for (int r = 0; r < 4; ++r) {
        int m = kg * 4 + r;
        __builtin_nontemporal_store(
            acc[r], out + ((size_t)(b * Tout + t0 + m)) * D + n);
    }
}

extern "C" void kernel_launch(void* const* d_in, const int* in_sizes, int n_in,
                              void* d_out, int out_size, void* d_ws, size_t ws_size,
                              hipStream_t stream) {
    const float* memory   = (const float*)d_in[0];
    const float* duration = (const float*)d_in[1];
    const float* sigma    = (const float*)d_in[2];
    const void*  mask     = d_in[4];          // d_in[3]=output_lengths (unused)

    int B    = in_sizes[3];
    int Tin  = in_sizes[1] / B;
    int D    = in_sizes[0] / (B * Tin);
    int Tout = out_size / (B * (D + Tin));

    float* out_up   = (float*)d_out;
    float* out_attn = out_up + (size_t)B * Tout * D;

    // workspace layout
    float* center = (float*)d_ws;
    float* amp    = center + (size_t)B * Tin;
    float* inv    = amp    + (size_t)B * Tin;
    float* iden   = inv    + (size_t)B * Tin;
    int*   lo     = (int*)(iden + (size_t)B * Tout);
    int*   cnt    = lo + (size_t)B * Tout;

    prep_k<<<B, Tin, 0, stream>>>(duration, sigma, mask,
                                  center, amp, inv, B, Tin);
    denom_k<<<dim3((Tout + 255) / 256, B), 256, 0, stream>>>(
        center, amp, inv, iden, lo, cnt, Tin, Tout);
    attn_k<<<B * Tin, 256, 0, stream>>>(center, amp, inv, iden,
                                        out_attn, Tin, Tout);
    int nUp = B * (Tout / TILE_T) * 4;        // 16384 blocks (16t x 64n each)
    upsample_k<<<nUp, 256, 0, stream>>>(
        memory, center, amp, inv, iden, lo, cnt, out_up, Tin, Tout, D);
}

// Round 10
// 66.688 us; speedup vs baseline: 1.3866x; 1.1792x over previous
//
#include <hip/hip_runtime.h>
#include <hip/hip_bf16.h>
#include <math.h>

#define HALF_LOG_2PI 0.9189385332046727f
#define WIN 32.0f
#define TILE_T 16

typedef float f32x4 __attribute__((ext_vector_type(4)));

// ---------------------------------------------------------------------------
// Kernel 1: mask-mode detect + per-row cumsum (center) + amp/inv_sigma.
// One block per batch row, blockDim = Tin.  (round-3 verbatim)
// ---------------------------------------------------------------------------
__global__ void prep_k(const float* __restrict__ duration,
                       const float* __restrict__ sigma,
                       const void* __restrict__ mask,
                       float* __restrict__ center,
                       float* __restrict__ amp,
                       float* __restrict__ inv_sigma,
                       int B, int Tin) {
    __shared__ float s[1024];
    __shared__ int s_not[2];
    int b = blockIdx.x, i = threadIdx.x;
    if (i < 2) s_not[i] = 0;
    __syncthreads();
    {   // detect over first B*Tin/4 words (minimum size over all modes)
        const unsigned int* mw = (const unsigned int*)mask;
        int nwords = (B * Tin) >> 2;
        int nI = 0, nF = 0;
        for (int k = i; k < nwords; k += blockDim.x) {
            unsigned int w = mw[k];
            nI |= (w != 0u && w != 1u);
            nF |= (w != 0u && w != 0x3F800000u);
        }
        if (nI) atomicOr(&s_not[0], 1);
        if (nF) atomicOr(&s_not[1], 1);
    }
    size_t gi = (size_t)b * Tin + i;
    float d = duration[gi];
    s[i] = d;
    __syncthreads();
    for (int off = 1; off < Tin; off <<= 1) {
        float v = (i >= off) ? s[i - off] : 0.0f;
        __syncthreads();
        s[i] += v;
        __syncthreads();
    }
    float c = s[i] - 0.5f * d;
    int mode = s_not[0] ? (s_not[1] ? 2 : 1) : 0;
    bool m;
    if (mode == 0)      m = ((const int*)mask)[gi] != 0;
    else if (mode == 1) m = ((const float*)mask)[gi] != 0.0f;
    else                m = ((const unsigned char*)mask)[gi] != 0;
    float sg = sigma[gi];
    center[gi]    = c;
    inv_sigma[gi] = 1.0f / sg;
    amp[gi]       = m ? 0.0f : __expf(-__logf(sg) - HALF_LOG_2PI);
}

// ---------------------------------------------------------------------------
// Kernel 2: inv_den / lo / cnt per (b,t).  (round-3 verbatim)
// ---------------------------------------------------------------------------
__global__ __launch_bounds__(256) void denom_k(
        const float* __restrict__ center, const float* __restrict__ amp,
        const float* __restrict__ inv_sigma,
        float* __restrict__ inv_den, int* __restrict__ lo_out,
        int* __restrict__ cnt_out, int Tin, int Tout) {
    __shared__ float sc[1024], sa[1024], si[1024];
    int b = blockIdx.y;
    int t = blockIdx.x * 256 + threadIdx.x;
    for (int i = threadIdx.x; i < Tin; i += 256) {
        size_t g = (size_t)b * Tin + i;
        sc[i] = center[g]; sa[i] = amp[g]; si[i] = inv_sigma[g];
    }
    __syncthreads();
    if (t >= Tout) return;
    float tf = (float)t;
    int lo = 0, hi = Tin;
    while (lo < hi) {                 // first i with center >= t - WIN
        int mid = (lo + hi) >> 1;
        if (sc[mid] < tf - WIN) lo = mid + 1; else hi = mid;
    }
    float sum = 0.0f;
    int i = lo;
    for (; i < Tin; ++i) {
        float cc = sc[i];
        if (cc > tf + WIN) break;
        float z = (tf - cc) * si[i];
        sum += sa[i] * __expf(-0.5f * z * z);
    }
    size_t g = (size_t)b * Tout + t;
    inv_den[g]  = 1.0f / (sum + 1e-8f);
    lo_out[g]   = lo;
    cnt_out[g]  = i - lo;
}

// ---------------------------------------------------------------------------
// Kernel 3: attn rows, one block per (b,i).  (round-3 verbatim)
// ---------------------------------------------------------------------------
__global__ __launch_bounds__(256) void attn_k(
        const float* __restrict__ center, const float* __restrict__ amp,
        const float* __restrict__ inv_sigma, const float* __restrict__ inv_den,
        float* __restrict__ attn, int Tin, int Tout) {
    int bi = blockIdx.x;
    int b  = bi / Tin;
    float c = center[bi], a = amp[bi], inv = inv_sigma[bi];
    const float* iden = inv_den + (size_t)b * Tout;
    float* row = attn + (size_t)bi * Tout;
    for (int t4 = threadIdx.x * 4; t4 < Tout; t4 += 256 * 4) {
        f32x4 rv;
        if ((float)(t4 + 3) < c - WIN || (float)t4 > c + WIN) {
            rv = (f32x4)0.0f;
        } else {
            #pragma unroll
            for (int j = 0; j < 4; ++j) {
                float dlt = (float)(t4 + j) - c;
                if (fabsf(dlt) < WIN) {
                    float z = dlt * inv;
                    rv[j] = a * __expf(-0.5f * z * z) * iden[t4 + j];
                } else rv[j] = 0.0f;
            }
        }
        __builtin_nontemporal_store(rv, (f32x4*)(row + t4));
    }
}

// ---------------------------------------------------------------------------
// Kernel 4: upsample, register-blocked across d.
// Block = 64 threads = ONE wave per (b, 16-frame tile). Each lane owns 4
// d-columns (d, d+64, d+128, d+192), so the 16 broadcast ds_read_b128 per
// 4-token chunk feed 4x the outputs (total LDS traffic /4 vs round-3).
// acc[16][4] fp32 in registers; fully coalesced 256 B global reads/writes.
// ---------------------------------------------------------------------------
__global__ __launch_bounds__(64) void upsample_k(
        const float* __restrict__ mem, const float* __restrict__ center,
        const float* __restrict__ amp, const float* __restrict__ inv_sigma,
        const float* __restrict__ inv_den, const int* __restrict__ lo_ws,
        const int* __restrict__ cnt_ws, float* __restrict__ out,
        int Tin, int Tout, int D) {
    __shared__ __align__(16) float w_s[TILE_T][128];
    __shared__ float s_iden[TILE_T];
    __shared__ int s_lo, s_cnt;
    int nwg = gridDim.x;
    int wid = blockIdx.x;
    int work = wid;
    if ((nwg & 7) == 0) {                 // XCD-chunked swizzle (8 XCDs)
        int chunk = nwg >> 3;
        work = (wid & 7) * chunk + (wid >> 3);
    }
    int tpb = Tout / TILE_T;
    int b   = work / tpb;
    int t0  = (work - b * tpb) * TILE_T;
    int tid = threadIdx.x;
    if (tid == 0) {
        size_t g0 = (size_t)b * Tout + t0;
        size_t g1 = g0 + (TILE_T - 1);
        int lo0 = lo_ws[g0];
        int cnt = lo_ws[g1] + cnt_ws[g1] - lo0;
        s_lo  = lo0;
        s_cnt = cnt > 128 ? 128 : cnt;    // mathematically <= ~81 (spacing>=1)
    }
    if (tid < TILE_T) s_iden[tid] = inv_den[(size_t)b * Tout + t0 + tid];
    __syncthreads();
    int lo0 = s_lo, wcnt = s_cnt;
    // normalized weights (32 slots/thread), coalesced center/amp/inv reads
    for (int id = tid; id < TILE_T * 128; id += 64) {
        int f = id >> 7, w = id & 127;
        float wgt = 0.0f;
        int i = lo0 + w;
        if (w < wcnt && i < Tin) {
            size_t gi = (size_t)b * Tin + i;
            float dlt = (float)(t0 + f) - center[gi];
            if (fabsf(dlt) < WIN) {
                float z = dlt * inv_sigma[gi];
                wgt = amp[gi] * __expf(-0.5f * z * z) * s_iden[f];
            }
        }
        w_s[f][w] = wgt;
    }
    __syncthreads();

    float acc[TILE_T][4];
    #pragma unroll
    for (int f = 0; f < TILE_T; ++f)
        #pragma unroll
        for (int dc = 0; dc < 4; ++dc) acc[f][dc] = 0.0f;

    const float* mrow = mem + ((size_t)b * Tin + lo0) * D + tid;
    int w4 = wcnt & ~3;
    for (int w = 0; w < w4; w += 4) {
        float m[4][4];                    // [w-in-chunk][d-col]
        #pragma unroll
        for (int ww = 0; ww < 4; ++ww)
            #pragma unroll
            for (int dc = 0; dc < 4; ++dc)
                m[ww][dc] = mrow[(size_t)(w + ww) * D + dc * 64];
        #pragma unroll
        for (int f = 0; f < TILE_T; ++f) {
            f32x4 wv = *(const f32x4*)&w_s[f][w];   // broadcast b128
            #pragma unroll
            for (int dc = 0; dc < 4; ++dc)
                acc[f][dc] += wv.x * m[0][dc] + wv.y * m[1][dc]
                            + wv.z * m[2][dc] + wv.w * m[3][dc];
        }
    }
    for (int w = w4; w < wcnt; ++w) {
        float m[4];
        #pragma unroll
        for (int dc = 0; dc < 4; ++dc) m[dc] = mrow[(size_t)w * D + dc * 64];
        #pragma unroll
        for (int f = 0; f < TILE_T; ++f) {
            float wgt = w_s[f][w];
            #pragma unroll
            for (int dc = 0; dc < 4; ++dc) acc[f][dc] += wgt * m[dc];
        }
    }
    float* obase = out + ((size_t)b * Tout + t0) * D + tid;
    #pragma unroll
    for (int f = 0; f < TILE_T; ++f)
        #pragma unroll
        for (int dc = 0; dc < 4; ++dc)
            __builtin_nontemporal_store(acc[f][dc],
                                        obase + (size_t)f * D + dc * 64);
}

extern "C" void kernel_launch(void* const* d_in, const int* in_sizes, int n_in,
                              void* d_out, int out_size, void* d_ws, size_t ws_size,
                              hipStream_t stream) {
    const float* memory   = (const float*)d_in[0];
    const float* duration = (const float*)d_in[1];
    const float* sigma    = (const float*)d_in[2];
    const void*  mask     = d_in[4];          // d_in[3]=output_lengths (unused)

    int B    = in_sizes[3];
    int Tin  = in_sizes[1] / B;
    int D    = in_sizes[0] / (B * Tin);
    int Tout = out_size / (B * (D + Tin));

    float* out_up   = (float*)d_out;
    float* out_attn = out_up + (size_t)B * Tout * D;

    // workspace layout
    float* center = (float*)d_ws;
    float* amp    = center + (size_t)B * Tin;
    float* inv    = amp    + (size_t)B * Tin;
    float* iden   = inv    + (size_t)B * Tin;
    int*   lo     = (int*)(iden + (size_t)B * Tout);
    int*   cnt    = lo + (size_t)B * Tout;

    prep_k<<<B, Tin, 0, stream>>>(duration, sigma, mask,
                                  center, amp, inv, B, Tin);
    denom_k<<<dim3((Tout + 255) / 256, B), 256, 0, stream>>>(
        center, amp, inv, iden, lo, cnt, Tin, Tout);
    attn_k<<<B * Tin, 256, 0, stream>>>(center, amp, inv, iden,
                                        out_attn, Tin, Tout);
    upsample_k<<<(B * Tout) / TILE_T, 64, 0, stream>>>(
        memory, center, amp, inv, iden, lo, cnt, out_up, Tin, Tout, D);
}